// Round 1
// baseline (217.438 us; speedup 1.0000x reference)
//
#include <hip/hip_runtime.h>
#include <hip/hip_bf16.h>

// Problem constants: B=16, N=1024, D=768 -> T=16384 tokens.
#define T_TOK   16384
#define D_DIM   768
#define ROWB    1536          // bytes per row (768 * 2B bf16)
#define INV_TEMP (1.0f/0.07f)

typedef __bf16 bf16x8 __attribute__((ext_vector_type(8)));
typedef float  f32x4  __attribute__((ext_vector_type(4)));
typedef unsigned int u32;

// ---------- order-preserving float <-> uint mapping for atomicMax ----------
__device__ __forceinline__ u32 f2u(float f) {
    u32 b = __float_as_uint(f);
    return (b & 0x80000000u) ? ~b : (b | 0x80000000u);
}
__device__ __forceinline__ float u2f(u32 u) {
    u32 b = (u & 0x80000000u) ? (u & 0x7FFFFFFFu) : ~u;
    return __uint_as_float(b);
}

// ---------- async global->LDS, 16B per lane ----------
__device__ __forceinline__ void gload16(const void* g, void* l) {
    __builtin_amdgcn_global_load_lds((const __attribute__((address_space(1))) u32*)g,
                                     (__attribute__((address_space(3))) u32*)l,
                                     16, 0, 0);
}

// ============================================================================
// K1: deterministic class-wise prefix scan of labels.
// meta[0]=R (count label==0), meta[1]=F (count label==1), meta[2]=Rpad.
// pos[i] = index of token i within its class.
// ============================================================================
__global__ void k_scan(const int* __restrict__ labels, int* __restrict__ pos,
                       int* __restrict__ meta)
{
    __shared__ int sr[256], sf[256];
    const int t = threadIdx.x;
    const int base = t * 64;
    int cr = 0, cf = 0;
    for (int i = 0; i < 64; ++i) {
        int v = labels[base + i];
        cr += (v == 0);
        cf += (v == 1);
    }
    sr[t] = cr; sf[t] = cf;
    __syncthreads();
    if (t == 0) {
        int ar = 0, af = 0;
        for (int i = 0; i < 256; ++i) {
            int r = sr[i]; sr[i] = ar; ar += r;
            int f = sf[i]; sf[i] = af; af += f;
        }
        meta[0] = ar;
        meta[1] = af;
        meta[2] = (ar + 127) & ~127;   // Rpad
    }
    __syncthreads();
    int pr = sr[t], pf = sf[t];
    for (int i = 0; i < 64; ++i) {
        int v = labels[base + i];
        pos[base + i] = (v == 0) ? pr++ : pf++;
    }
}

// ============================================================================
// K2: L2-normalize each token row (f32), convert to bf16, scatter compacted:
// real rows -> Xall[0..R), fake rows -> Xall[Rpad..Rpad+F).
// ============================================================================
__global__ void k_norm(const float* __restrict__ x, const int* __restrict__ labels,
                       const int* __restrict__ pos, const int* __restrict__ meta,
                       __hip_bfloat16* __restrict__ Xall)
{
    const int row = blockIdx.x;
    const int t = threadIdx.x;
    const float* xr = x + (size_t)row * D_DIM;
    float a0 = xr[t], a1 = xr[t + 256], a2 = xr[t + 512];
    float ss = a0 * a0 + a1 * a1 + a2 * a2;
    #pragma unroll
    for (int m = 32; m >= 1; m >>= 1) ss += __shfl_xor(ss, m);
    __shared__ float sred[4];
    if ((t & 63) == 0) sred[t >> 6] = ss;
    __syncthreads();
    float tot = sred[0] + sred[1] + sred[2] + sred[3];
    float inv = 1.0f / fmaxf(sqrtf(tot), 1e-12f);
    int lab = labels[row];
    int base = (lab == 0) ? pos[row] : (meta[2] + pos[row]);
    __hip_bfloat16* dst = Xall + (size_t)base * D_DIM;
    dst[t]       = __float2bfloat16(a0 * inv);
    dst[t + 256] = __float2bfloat16(a1 * inv);
    dst[t + 512] = __float2bfloat16(a2 * inv);
}

// ============================================================================
// K3: 128x128-tile bf16 MFMA "GEMM" over the RxF block; instead of storing C,
// track per-row max (over fake cols) and per-col max (over real rows) via
// atomicMax on the order-preserving uint mapping.
// LDS: A/B tiles [128 rows][64 k] bf16, XOR-swizzled (chunk ^= row&7) with
// pre-swizzled global source so global_load_lds' linear dest matches.
// ============================================================================
__global__ __launch_bounds__(256) void k_gemm(const __hip_bfloat16* __restrict__ Xall,
                                              const int* __restrict__ meta,
                                              u32* __restrict__ rowmax,
                                              u32* __restrict__ colmax)
{
    const int R = meta[0], Fc = meta[1], Rpad = meta[2];
    const int bm = blockIdx.x, bn = blockIdx.y;
    if (bm * 128 >= R || bn * 128 >= Fc) return;

    __shared__ __align__(16) char As[16384];
    __shared__ __align__(16) char Bs[16384];

    const int tid = threadIdx.x;
    const int w = tid >> 6, l = tid & 63;
    const int wm = w >> 1, wn = w & 1;
    const int lg = l >> 4, li = l & 15;

    const char* Abase = (const char*)Xall + (size_t)(bm * 128) * ROWB;
    const char* Bbase = (const char*)Xall + (size_t)(Rpad + bn * 128) * ROWB;

    const int r_st = tid >> 3;   // 0..31: row within 32-row issue group
    const int c_st = tid & 7;    // 0..7 : 16B chunk within row

    f32x4 zero4 = {0.f, 0.f, 0.f, 0.f};
    f32x4 acc[4][4];
    #pragma unroll
    for (int m = 0; m < 4; ++m)
        #pragma unroll
        for (int n = 0; n < 4; ++n) acc[m][n] = zero4;

    #pragma unroll 1
    for (int kt = 0; kt < 12; ++kt) {
        __syncthreads();
        const int koff = kt * 128;   // byte offset of this BK=64 chunk in a row
        #pragma unroll
        for (int i = 0; i < 4; ++i) {
            int r = i * 32 + r_st;
            int cs = (c_st ^ (r & 7)) * 16;   // pre-swizzled source chunk
            gload16(Abase + (size_t)r * ROWB + koff + cs, As + i * 4096 + w * 1024);
            gload16(Bbase + (size_t)r * ROWB + koff + cs, Bs + i * 4096 + w * 1024);
        }
        __syncthreads();
        #pragma unroll
        for (int kk = 0; kk < 2; ++kk) {
            bf16x8 af[4], bfr[4];
            #pragma unroll
            for (int m = 0; m < 4; ++m) {
                int row = wm * 64 + m * 16 + li;
                int kb = kk * 4 + lg;
                af[m] = *(const bf16x8*)(As + row * 128 + ((kb ^ (row & 7)) * 16));
            }
            #pragma unroll
            for (int n = 0; n < 4; ++n) {
                int row = wn * 64 + n * 16 + li;
                int kb = kk * 4 + lg;
                bfr[n] = *(const bf16x8*)(Bs + row * 128 + ((kb ^ (row & 7)) * 16));
            }
            #pragma unroll
            for (int m = 0; m < 4; ++m)
                #pragma unroll
                for (int n = 0; n < 4; ++n)
                    acc[m][n] = __builtin_amdgcn_mfma_f32_16x16x32_bf16(af[m], bfr[n], acc[m][n], 0, 0, 0);
        }
    }

    // ---------------- epilogue: row / col maxes ----------------
    // C/D layout (m89-verified): col = li, row = lg*4 + reg.
    const float MASKED = -3.0f;   // valid dots are in [-1,1]

    // row maxes (per real row, over fake cols)
    #pragma unroll
    for (int m = 0; m < 4; ++m) {
        #pragma unroll
        for (int reg = 0; reg < 4; ++reg) {
            float v = MASKED;
            #pragma unroll
            for (int n = 0; n < 4; ++n) {
                int gc = bn * 128 + wn * 64 + n * 16 + li;
                float xv = acc[m][n][reg];
                v = fmaxf(v, (gc < Fc) ? xv : MASKED);
            }
            v = fmaxf(v, __shfl_xor(v, 1));
            v = fmaxf(v, __shfl_xor(v, 2));
            v = fmaxf(v, __shfl_xor(v, 4));
            v = fmaxf(v, __shfl_xor(v, 8));
            int gr = bm * 128 + wm * 64 + m * 16 + lg * 4 + reg;
            if (li == 0 && gr < R) atomicMax(&rowmax[gr], f2u(v));
        }
    }

    // col maxes (per fake col, over real rows)
    #pragma unroll
    for (int n = 0; n < 4; ++n) {
        float v = MASKED;
        #pragma unroll
        for (int m = 0; m < 4; ++m) {
            #pragma unroll
            for (int reg = 0; reg < 4; ++reg) {
                int gr = bm * 128 + wm * 64 + m * 16 + lg * 4 + reg;
                float xv = acc[m][n][reg];
                v = fmaxf(v, (gr < R) ? xv : MASKED);
            }
        }
        v = fmaxf(v, __shfl_xor(v, 16));
        v = fmaxf(v, __shfl_xor(v, 32));
        int gc = bn * 128 + wn * 64 + n * 16 + li;
        if (lg == 0 && gc < Fc) atomicMax(&colmax[gc], f2u(v));
    }
}

// ============================================================================
// K4: map maxes -> loss terms, masked means, final scalar.
// ============================================================================
__global__ void k_final(const u32* __restrict__ rowmax, const u32* __restrict__ colmax,
                        const int* __restrict__ meta, float* __restrict__ out)
{
    const int R = meta[0], Fc = meta[1];
    const int t = threadIdx.x;
    float sr = 0.f, sf = 0.f;
    for (int i = t; i < R; i += 256) {
        u32 u = rowmax[i];
        float m = (u == 0u) ? -1e9f : u2f(u) * INV_TEMP;
        float sg = 1.0f / (1.0f + expf(-m));
        sr += -logf(1.0f - sg + 1e-6f);
    }
    for (int i = t; i < Fc; i += 256) {
        u32 u = colmax[i];
        float m = (u == 0u) ? -1e9f : u2f(u) * INV_TEMP;
        float sg = 1.0f / (1.0f + expf(-m));
        sf += -logf(1.0f - sg + 1e-6f);
    }
    #pragma unroll
    for (int msk = 32; msk >= 1; msk >>= 1) {
        sr += __shfl_xor(sr, msk);
        sf += __shfl_xor(sf, msk);
    }
    __shared__ float r4[4], f4[4];
    if ((t & 63) == 0) { r4[t >> 6] = sr; f4[t >> 6] = sf; }
    __syncthreads();
    if (t == 0) {
        float a = (r4[0] + r4[1] + r4[2] + r4[3]) / (float)((R > 0) ? R : 1);
        float b = (f4[0] + f4[1] + f4[2] + f4[3]) / (float)((Fc > 0) ? Fc : 1);
        out[0] = 0.5f * (a + b);
    }
}

// ============================================================================
extern "C" void kernel_launch(void* const* d_in, const int* in_sizes, int n_in,
                              void* d_out, int out_size, void* d_ws, size_t ws_size,
                              hipStream_t stream)
{
    (void)in_sizes; (void)n_in; (void)out_size; (void)ws_size;
    const float* x    = (const float*)d_in[0];
    const int* labels = (const int*)d_in[1];
    float* out        = (float*)d_out;

    char* ws = (char*)d_ws;
    int* meta = (int*)ws;                         // 4 ints
    int* pos  = (int*)(ws + 256);                 // 16384 ints
    __hip_bfloat16* Xall = (__hip_bfloat16*)(ws + 131072);          // 16640 rows x 768 bf16
    u32* rowmax = (u32*)(ws + 131072 + 25559040);                   // 16640 u32
    u32* colmax = rowmax + 16640;                                   // 16640 u32

    k_scan<<<1, 256, 0, stream>>>(labels, pos, meta);
    k_norm<<<T_TOK, 256, 0, stream>>>(x, labels, pos, meta, Xall);
    hipMemsetAsync(rowmax, 0, 2 * 16640 * sizeof(u32), stream);
    k_gemm<<<dim3(128, 128), 256, 0, stream>>>(Xall, meta, rowmax, colmax);
    k_final<<<1, 256, 0, stream>>>(rowmax, colmax, meta, out);
}

// Round 2
// 204.301 us; speedup vs baseline: 1.0643x; 1.0643x over previous
//
#include <hip/hip_runtime.h>
#include <hip/hip_bf16.h>

// Problem constants: B=16, N=1024, D=768 -> T=16384 tokens.
#define T_TOK   16384
#define D_DIM   768
#define ROWB    1536          // bytes per row (768 * 2B bf16)
#define INV_TEMP (1.0f/0.07f)
#define XROWS   17152         // Xall rows (Rpad<=R+255, +F, +tile slack)
#define XALL_BYTES (XROWS * ROWB)

typedef __bf16 bf16x8 __attribute__((ext_vector_type(8)));
typedef float  f32x4  __attribute__((ext_vector_type(4)));
typedef unsigned int u32;

// ---------- order-preserving float <-> uint mapping for atomicMax ----------
__device__ __forceinline__ u32 f2u(float f) {
    u32 b = __float_as_uint(f);
    return (b & 0x80000000u) ? ~b : (b | 0x80000000u);
}
__device__ __forceinline__ float u2f(u32 u) {
    u32 b = (u & 0x80000000u) ? (u & 0x7FFFFFFFu) : ~u;
    return __uint_as_float(b);
}

// ---------- async global->LDS, 16B per lane ----------
__device__ __forceinline__ void gload16(const void* g, void* l) {
    __builtin_amdgcn_global_load_lds((const __attribute__((address_space(1))) u32*)g,
                                     (__attribute__((address_space(3))) u32*)l,
                                     16, 0, 0);
}

// ============================================================================
// K1: deterministic class-wise prefix scan of labels.
// meta[0]=R, meta[1]=F, meta[2]=Rpad (256-aligned).
// ============================================================================
__global__ void k_scan(const int* __restrict__ labels, int* __restrict__ pos,
                       int* __restrict__ meta)
{
    __shared__ int sr[256], sf[256];
    const int t = threadIdx.x;
    const int base = t * 64;
    int cr = 0, cf = 0;
    for (int i = 0; i < 64; ++i) {
        int v = labels[base + i];
        cr += (v == 0);
        cf += (v == 1);
    }
    sr[t] = cr; sf[t] = cf;
    __syncthreads();
    if (t == 0) {
        int ar = 0, af = 0;
        for (int i = 0; i < 256; ++i) {
            int r = sr[i]; sr[i] = ar; ar += r;
            int f = sf[i]; sf[i] = af; af += f;
        }
        meta[0] = ar;
        meta[1] = af;
        meta[2] = (ar + 255) & ~255;   // Rpad, 256-aligned for 256-tiles
    }
    __syncthreads();
    int pr = sr[t], pf = sf[t];
    for (int i = 0; i < 64; ++i) {
        int v = labels[base + i];
        pos[base + i] = (v == 0) ? pr++ : pf++;
    }
}

// ============================================================================
// K2: L2-normalize each token row (f32), convert to bf16, scatter compacted.
// ============================================================================
__global__ void k_norm(const float* __restrict__ x, const int* __restrict__ labels,
                       const int* __restrict__ pos, const int* __restrict__ meta,
                       __hip_bfloat16* __restrict__ Xall)
{
    const int row = blockIdx.x;
    const int t = threadIdx.x;
    const float* xr = x + (size_t)row * D_DIM;
    float a0 = xr[t], a1 = xr[t + 256], a2 = xr[t + 512];
    float ss = a0 * a0 + a1 * a1 + a2 * a2;
    #pragma unroll
    for (int m = 32; m >= 1; m >>= 1) ss += __shfl_xor(ss, m);
    __shared__ float sred[4];
    if ((t & 63) == 0) sred[t >> 6] = ss;
    __syncthreads();
    float tot = sred[0] + sred[1] + sred[2] + sred[3];
    float inv = 1.0f / fmaxf(sqrtf(tot), 1e-12f);
    int lab = labels[row];
    int base = (lab == 0) ? pos[row] : (meta[2] + pos[row]);
    __hip_bfloat16* dst = Xall + (size_t)base * D_DIM;
    dst[t]       = __float2bfloat16(a0 * inv);
    dst[t + 256] = __float2bfloat16(a1 * inv);
    dst[t + 512] = __float2bfloat16(a2 * inv);
}

// ============================================================================
// K3: 256x256-tile, BK=64, 8-wave (2Mx4N), 8-phase interleave with counted
// vmcnt (T3+T4), XOR-swizzled LDS (T2), setprio around MFMA (T5).
//
// LDS (128 KiB): buf b in {0,1} at b*65536:
//   A0 (tile rows mq=0: 0-63,128-191)  @ +0      (16 KiB, 128 rows x 64 bf16)
//   A1 (tile rows mq=1: 64-127,192-255)@ +16384
//   B0 (per-wn col-groups nq=0)        @ +32768
//   B1                                 @ +49152
// Region row encodings chosen so each wave's MFMA reads are region-local.
// Chunk swizzle: LDS[row][c] holds source chunk c^(row&7); staged via
// pre-swizzled global source (both-sides rule), read with the same XOR.
//
// Phase p computes quadrant (mq,nq) of its buffer's K-tile, order
// (0,0),(1,0),(1,1),(0,1); stage slots are placed one phase after each
// region's last read, and the group-boundary fused "vmcnt(4); s_barrier"
// guarantees every region arrived before its first read (derivation in
// round notes -- strict, no timing assumptions).
// ============================================================================
#define MFMA16(a,b,c) __builtin_amdgcn_mfma_f32_16x16x32_bf16(a,b,c,0,0,0)

#define LA(buf,mq) (lds + (buf)*65536 + (mq)*16384)
#define LB(buf,nq) (lds + (buf)*65536 + 32768 + (nq)*16384)

#define STAGE_A(buf,mq,kt) do { \
    gload16(sA0[mq] + (kt)*128, LA(buf,mq) + wq); \
    gload16(sA1[mq] + (kt)*128, LA(buf,mq) + wq + 8192); } while(0)
#define STAGE_B(buf,nq,kt) do { \
    gload16(sB0[nq] + (kt)*128, LB(buf,nq) + wq); \
    gload16(sB1[nq] + (kt)*128, LB(buf,nq) + wq + 8192); } while(0)

#define BAR    __builtin_amdgcn_s_barrier()
#define GUARD4 asm volatile("s_waitcnt vmcnt(4)\n\ts_barrier" ::: "memory")

#define PHASE(buf,mq,nq,...) do { \
    bf16x8 af[4][2], bv[2][2]; \
    _Pragma("unroll") \
    for (int mm = 0; mm < 4; ++mm) { \
        af[mm][0] = *(const bf16x8*)(LA(buf,mq) + aBase + mm*2048 + cb0); \
        af[mm][1] = *(const bf16x8*)(LA(buf,mq) + aBase + mm*2048 + cb1); } \
    _Pragma("unroll") \
    for (int nn = 0; nn < 2; ++nn) { \
        bv[nn][0] = *(const bf16x8*)(LB(buf,nq) + bBase + nn*2048 + cb0); \
        bv[nn][1] = *(const bf16x8*)(LB(buf,nq) + bBase + nn*2048 + cb1); } \
    __VA_ARGS__; \
    __builtin_amdgcn_s_barrier(); \
    __builtin_amdgcn_s_setprio(1); \
    _Pragma("unroll") \
    for (int mm = 0; mm < 4; ++mm) { \
        _Pragma("unroll") \
        for (int nn = 0; nn < 2; ++nn) { \
            acc[(mq)*4+mm][(nq)*2+nn] = MFMA16(af[mm][0], bv[nn][0], acc[(mq)*4+mm][(nq)*2+nn]); \
            acc[(mq)*4+mm][(nq)*2+nn] = MFMA16(af[mm][1], bv[nn][1], acc[(mq)*4+mm][(nq)*2+nn]); } } \
    __builtin_amdgcn_s_setprio(0); \
} while(0)

__global__ __launch_bounds__(512, 2) void k_gemm(const __hip_bfloat16* __restrict__ Xall,
                                                 const int* __restrict__ meta,
                                                 u32* __restrict__ rowmax,
                                                 u32* __restrict__ colmax)
{
    const int R = meta[0], Fc = meta[1], Rpad = meta[2];
    const int bm = blockIdx.x, bn = blockIdx.y;
    if (bm * 256 >= R || bn * 256 >= Fc) return;

    __shared__ __align__(16) char lds[131072];

    const int tid = threadIdx.x;
    const int w  = tid >> 6, l = tid & 63;
    const int wm = w >> 2, wn = w & 3;
    const int lg = l >> 4, li = l & 15;
    const int wq = w * 1024;

    // staging geometry: thread covers region rows row0 (j=0) and row0+64 (j=1)
    const int row0 = w * 8 + (l >> 3);                  // 0..63
    const int ch   = ((l & 7) ^ (row0 & 7)) * 16;       // pre-swizzled src chunk
    const int brow = ((row0 >> 5) << 6) + (row0 & 31);  // B tile-row low part

    const char* Ab = (const char*)Xall + (size_t)(bm * 256) * ROWB;
    const char* Bb = (const char*)Xall + (size_t)(Rpad + bn * 256) * ROWB;

    const char* sA0[2]; const char* sA1[2]; const char* sB0[2]; const char* sB1[2];
    #pragma unroll
    for (int q = 0; q < 2; ++q) {
        sA0[q] = Ab + (size_t)(q * 64 + row0) * ROWB + ch;        // region rows 0-63
        sA1[q] = Ab + (size_t)(128 + q * 64 + row0) * ROWB + ch;  // region rows 64-127
        sB0[q] = Bb + (size_t)(q * 32 + brow) * ROWB + ch;
        sB1[q] = Bb + (size_t)(128 + q * 32 + brow) * ROWB + ch;
    }

    // MFMA read geometry
    const int aBase = (wm * 64 + li) * 128;   // region row * 128B
    const int bBase = (wn * 32 + li) * 128;
    const int sw  = li & 7;                   // == (region_row & 7) on read side
    const int cb0 = (lg ^ sw) * 16;           // kk=0 swizzled chunk byte offset
    const int cb1 = ((4 + lg) ^ sw) * 16;     // kk=1

    f32x4 acc[8][4];
    #pragma unroll
    for (int m = 0; m < 8; ++m)
        #pragma unroll
        for (int n = 0; n < 4; ++n)
            acc[m][n] = (f32x4){0.f, 0.f, 0.f, 0.f};

    // prologue: kt0 full into buf0; kt1's B0,A1 into buf1 (slots "prev ph6/ph7")
    STAGE_A(0,0,0); STAGE_A(0,1,0); STAGE_B(0,0,0); STAGE_B(0,1,0);
    STAGE_B(1,0,1); STAGE_A(1,1,1);
    GUARD4;   // kt0 arrived (4 = kt1's B0,A1 still in flight, guarded at end-ph3)

    #pragma unroll 1
    for (int it = 0; it < 6; ++it) {
        const int kt1 = 2 * it + 1;
        int ktA = 2 * it + 2; if (ktA > 11) ktA = 11;   // clamped: staged, never read
        int ktB = 2 * it + 3; if (ktB > 11) ktB = 11;

        PHASE(0,0,0, STAGE_A(1,0,kt1); STAGE_B(1,1,kt1));  // reads A0,B0 buf0
        BAR;
        PHASE(0,1,0, );                                     // A1,B0
        BAR;
        PHASE(0,1,1, STAGE_B(0,0,ktA));                     // A1,B1 (B0 freed)
        BAR;
        PHASE(0,0,1, STAGE_A(0,1,ktA));                     // A0,B1 (A1 freed)
        GUARD4;   // buf1 tile kt1 fully arrived
        PHASE(1,0,0, STAGE_A(0,0,ktA); STAGE_B(0,1,ktA));   // A0,B0 buf1
        BAR;
        PHASE(1,1,0, );
        BAR;
        PHASE(1,1,1, STAGE_B(1,0,ktB));
        BAR;
        PHASE(1,0,1, STAGE_A(1,1,ktB));
        GUARD4;   // buf0 tile ktA fully arrived
    }

    // ---------------- epilogue: row / col maxes ----------------
    // C/D layout (m89): col = li, row = lg*4 + reg.
    const float MASKED = -3.0f;

    #pragma unroll
    for (int m = 0; m < 8; ++m) {
        #pragma unroll
        for (int reg = 0; reg < 4; ++reg) {
            float v = MASKED;
            #pragma unroll
            for (int n = 0; n < 4; ++n) {
                int gc = bn * 256 + wn * 64 + n * 16 + li;
                v = fmaxf(v, (gc < Fc) ? acc[m][n][reg] : MASKED);
            }
            v = fmaxf(v, __shfl_xor(v, 1));
            v = fmaxf(v, __shfl_xor(v, 2));
            v = fmaxf(v, __shfl_xor(v, 4));
            v = fmaxf(v, __shfl_xor(v, 8));
            int gr = bm * 256 + wm * 128 + m * 16 + lg * 4 + reg;
            if (li == 0 && gr < R) atomicMax(&rowmax[gr], f2u(v));
        }
    }

    #pragma unroll
    for (int n = 0; n < 4; ++n) {
        float v = MASKED;
        #pragma unroll
        for (int m = 0; m < 8; ++m) {
            #pragma unroll
            for (int reg = 0; reg < 4; ++reg) {
                int gr = bm * 256 + wm * 128 + m * 16 + lg * 4 + reg;
                v = fmaxf(v, (gr < R) ? acc[m][n][reg] : MASKED);
            }
        }
        v = fmaxf(v, __shfl_xor(v, 16));
        v = fmaxf(v, __shfl_xor(v, 32));
        int gc = bn * 256 + wn * 64 + n * 16 + li;
        if (lg == 0 && gc < Fc) atomicMax(&colmax[gc], f2u(v));
    }
}

// ============================================================================
// K4: map maxes -> loss terms, masked means, final scalar.
// ============================================================================
__global__ void k_final(const u32* __restrict__ rowmax, const u32* __restrict__ colmax,
                        const int* __restrict__ meta, float* __restrict__ out)
{
    const int R = meta[0], Fc = meta[1];
    const int t = threadIdx.x;
    float sr = 0.f, sf = 0.f;
    for (int i = t; i < R; i += 256) {
        u32 u = rowmax[i];
        float m = (u == 0u) ? -1e9f : u2f(u) * INV_TEMP;
        float sg = 1.0f / (1.0f + expf(-m));
        sr += -logf(1.0f - sg + 1e-6f);
    }
    for (int i = t; i < Fc; i += 256) {
        u32 u = colmax[i];
        float m = (u == 0u) ? -1e9f : u2f(u) * INV_TEMP;
        float sg = 1.0f / (1.0f + expf(-m));
        sf += -logf(1.0f - sg + 1e-6f);
    }
    #pragma unroll
    for (int msk = 32; msk >= 1; msk >>= 1) {
        sr += __shfl_xor(sr, msk);
        sf += __shfl_xor(sf, msk);
    }
    __shared__ float r4[4], f4[4];
    if ((t & 63) == 0) { r4[t >> 6] = sr; f4[t >> 6] = sf; }
    __syncthreads();
    if (t == 0) {
        float a = (r4[0] + r4[1] + r4[2] + r4[3]) / (float)((R > 0) ? R : 1);
        float b = (f4[0] + f4[1] + f4[2] + f4[3]) / (float)((Fc > 0) ? Fc : 1);
        out[0] = 0.5f * (a + b);
    }
}

// ============================================================================
extern "C" void kernel_launch(void* const* d_in, const int* in_sizes, int n_in,
                              void* d_out, int out_size, void* d_ws, size_t ws_size,
                              hipStream_t stream)
{
    (void)in_sizes; (void)n_in; (void)out_size; (void)ws_size;
    const float* x    = (const float*)d_in[0];
    const int* labels = (const int*)d_in[1];
    float* out        = (float*)d_out;

    char* ws = (char*)d_ws;
    int* meta = (int*)ws;                                  // 4 ints
    int* pos  = (int*)(ws + 256);                          // 16384 ints
    __hip_bfloat16* Xall = (__hip_bfloat16*)(ws + 131072); // XROWS x 768 bf16
    u32* rowmax = (u32*)(ws + 131072 + XALL_BYTES);        // 16384 u32
    u32* colmax = rowmax + 16384;                          // 16384 u32

    k_scan<<<1, 256, 0, stream>>>(labels, pos, meta);
    k_norm<<<T_TOK, 256, 0, stream>>>(x, labels, pos, meta, Xall);
    hipMemsetAsync(rowmax, 0, 2 * 16384 * sizeof(u32), stream);
    k_gemm<<<dim3(64, 64), 512, 0, stream>>>(Xall, meta, rowmax, colmax);
    k_final<<<1, 256, 0, stream>>>(rowmax, colmax, meta, out);
}

// Round 3
// 180.911 us; speedup vs baseline: 1.2019x; 1.1293x over previous
//
#include <hip/hip_runtime.h>
#include <hip/hip_bf16.h>

// Problem constants: B=16, N=1024, D=768 -> T=16384 tokens.
#define T_TOK   16384
#define D_DIM   768
#define ROWB    1536          // bytes per row (768 * 2B bf16)
#define INV_TEMP (1.0f/0.07f)
#define XROWS   17152
#define XALL_BYTES (XROWS * ROWB)

typedef __bf16 bf16x8 __attribute__((ext_vector_type(8)));
typedef float  f32x4  __attribute__((ext_vector_type(4)));
typedef unsigned int u32;

__device__ __forceinline__ u32 f2u(float f) {
    u32 b = __float_as_uint(f);
    return (b & 0x80000000u) ? ~b : (b | 0x80000000u);
}
__device__ __forceinline__ float u2f(u32 u) {
    u32 b = (u & 0x80000000u) ? (u & 0x7FFFFFFFu) : ~u;
    return __uint_as_float(b);
}

__device__ __forceinline__ void gload16(const void* g, void* l) {
    __builtin_amdgcn_global_load_lds((const __attribute__((address_space(1))) u32*)g,
                                     (__attribute__((address_space(3))) u32*)l,
                                     16, 0, 0);
}

// ============================================================================
// K1: class-wise prefix scan. meta[0]=R, meta[1]=F, meta[2]=Rpad(256-aligned).
// ============================================================================
__global__ void k_scan(const int* __restrict__ labels, int* __restrict__ pos,
                       int* __restrict__ meta)
{
    __shared__ int sr[256], sf[256];
    const int t = threadIdx.x;
    const int base = t * 64;
    int cr = 0, cf = 0;
    for (int i = 0; i < 64; ++i) {
        int v = labels[base + i];
        cr += (v == 0);
        cf += (v == 1);
    }
    sr[t] = cr; sf[t] = cf;
    __syncthreads();
    if (t == 0) {
        int ar = 0, af = 0;
        for (int i = 0; i < 256; ++i) {
            int r = sr[i]; sr[i] = ar; ar += r;
            int f = sf[i]; sf[i] = af; af += f;
        }
        meta[0] = ar;
        meta[1] = af;
        meta[2] = (ar + 255) & ~255;
    }
    __syncthreads();
    int pr = sr[t], pf = sf[t];
    for (int i = 0; i < 64; ++i) {
        int v = labels[base + i];
        pos[base + i] = (v == 0) ? pr++ : pf++;
    }
}

// ============================================================================
// K2: L2-normalize rows, bf16-convert, scatter compacted by class.
// ============================================================================
__global__ void k_norm(const float* __restrict__ x, const int* __restrict__ labels,
                       const int* __restrict__ pos, const int* __restrict__ meta,
                       __hip_bfloat16* __restrict__ Xall)
{
    const int row = blockIdx.x;
    const int t = threadIdx.x;
    const float* xr = x + (size_t)row * D_DIM;
    float a0 = xr[t], a1 = xr[t + 256], a2 = xr[t + 512];
    float ss = a0 * a0 + a1 * a1 + a2 * a2;
    #pragma unroll
    for (int m = 32; m >= 1; m >>= 1) ss += __shfl_xor(ss, m);
    __shared__ float sred[4];
    if ((t & 63) == 0) sred[t >> 6] = ss;
    __syncthreads();
    float tot = sred[0] + sred[1] + sred[2] + sred[3];
    float inv = 1.0f / fmaxf(sqrtf(tot), 1e-12f);
    int lab = labels[row];
    int base = (lab == 0) ? pos[row] : (meta[2] + pos[row]);
    __hip_bfloat16* dst = Xall + (size_t)base * D_DIM;
    dst[t]       = __float2bfloat16(a0 * inv);
    dst[t + 256] = __float2bfloat16(a1 * inv);
    dst[t + 512] = __float2bfloat16(a2 * inv);
}

// ============================================================================
// K3: streaming 256x256 tiles. Each block owns one bm and iterates bn =
// grp, grp+8, grp+16, ... -- the 8-phase pipeline's staging cursor runs
// linearly over (bn,kt) so the pipeline NEVER drains across bn boundaries.
// Per-bn epilogue is register-only (colmax flush + acc reset); rowmax is
// accumulated in registers and flushed once at the end.
// Same verified LDS swizzle / region layout / phase slots as round 2.
// ============================================================================
#define MFMA16(a,b,c) __builtin_amdgcn_mfma_f32_16x16x32_bf16(a,b,c,0,0,0)

#define LA(buf,mq) (lds + (buf)*65536 + (mq)*16384)
#define LB(buf,nq) (lds + (buf)*65536 + 32768 + (nq)*16384)

// step s -> (bi = s/12, kt = s%12); all wave-uniform scalar math.
#define STAGE_A(buf,mq,s) do { \
    int kt_ = (s) - ((s)/12)*12; \
    gload16(sA0[mq] + kt_*128, LA(buf,mq) + wq); \
    gload16(sA1[mq] + kt_*128, LA(buf,mq) + wq + 8192); } while(0)
#define STAGE_B(buf,nq,s) do { \
    int bi_ = (s)/12, kt_ = (s) - bi_*12; \
    const char* bp_ = Bb + (size_t)(grp + 8*bi_) * (256*ROWB); \
    gload16(bp_ + boff0[nq] + kt_*128, LB(buf,nq) + wq); \
    gload16(bp_ + boff1[nq] + kt_*128, LB(buf,nq) + wq + 8192); } while(0)

#define BAR    __builtin_amdgcn_s_barrier()
#define GUARD4 asm volatile("s_waitcnt vmcnt(4)\n\ts_barrier" ::: "memory")

#define PHASE(buf,mq,nq,...) do { \
    bf16x8 af[4][2], bv[2][2]; \
    _Pragma("unroll") \
    for (int mm = 0; mm < 4; ++mm) { \
        af[mm][0] = *(const bf16x8*)(LA(buf,mq) + aBase + mm*2048 + cb0); \
        af[mm][1] = *(const bf16x8*)(LA(buf,mq) + aBase + mm*2048 + cb1); } \
    _Pragma("unroll") \
    for (int nn = 0; nn < 2; ++nn) { \
        bv[nn][0] = *(const bf16x8*)(LB(buf,nq) + bBase + nn*2048 + cb0); \
        bv[nn][1] = *(const bf16x8*)(LB(buf,nq) + bBase + nn*2048 + cb1); } \
    __VA_ARGS__; \
    __builtin_amdgcn_s_barrier(); \
    __builtin_amdgcn_s_setprio(1); \
    _Pragma("unroll") \
    for (int mm = 0; mm < 4; ++mm) { \
        _Pragma("unroll") \
        for (int nn = 0; nn < 2; ++nn) { \
            acc[(mq)*4+mm][(nq)*2+nn] = MFMA16(af[mm][0], bv[nn][0], acc[(mq)*4+mm][(nq)*2+nn]); \
            acc[(mq)*4+mm][(nq)*2+nn] = MFMA16(af[mm][1], bv[nn][1], acc[(mq)*4+mm][(nq)*2+nn]); } } \
    __builtin_amdgcn_s_setprio(0); \
} while(0)

__global__ __launch_bounds__(512, 2) void k_gemm(const __hip_bfloat16* __restrict__ Xall,
                                                 const int* __restrict__ meta,
                                                 u32* __restrict__ rowmax,
                                                 u32* __restrict__ colmax)
{
    const int R = meta[0], Fc = meta[1], Rpad = meta[2];

    // XCD-aware decode: lin%8 ~ XCD; bm == xcd (mod 8) so active blocks
    // spread 1/CU and each XCD's A panels stay L2-resident.
    const int lin = blockIdx.x;
    const int xcd = lin & 7, slot = lin >> 3;
    const int bm  = (slot & 7) * 8 + xcd;     // [0,64)
    const int grp = slot >> 3;                // [0,8)
    if (bm * 256 >= R) return;
    const int nbn = (Fc + 255) >> 8;
    const int nt  = (grp < nbn) ? ((nbn - grp + 7) >> 3) : 0;  // bn tiles: grp+8k
    if (nt == 0) return;
    const int NS = 12 * nt;                   // total K-steps in this block's stream

    __shared__ __align__(16) char lds[131072];

    const int tid = threadIdx.x;
    const int w  = tid >> 6, l = tid & 63;
    const int wm = w >> 2, wn = w & 3;
    const int lg = l >> 4, li = l & 15;
    const int wq = w * 1024;

    const int row0 = w * 8 + (l >> 3);
    const int ch   = ((l & 7) ^ (row0 & 7)) * 16;
    const int brow = ((row0 >> 5) << 6) + (row0 & 31);

    const char* Ab = (const char*)Xall + (size_t)(bm * 256) * ROWB;
    const char* Bb = (const char*)Xall + (size_t)Rpad * ROWB;

    const char* sA0[2]; const char* sA1[2];
    int boff0[2], boff1[2];
    #pragma unroll
    for (int q = 0; q < 2; ++q) {
        sA0[q] = Ab + (size_t)(q * 64 + row0) * ROWB + ch;
        sA1[q] = Ab + (size_t)(128 + q * 64 + row0) * ROWB + ch;
        boff0[q] = (q * 32 + brow) * ROWB + ch;
        boff1[q] = (128 + q * 32 + brow) * ROWB + ch;
    }

    const int aBase = (wm * 64 + li) * 128;
    const int bBase = (wn * 32 + li) * 128;
    const int sw  = li & 7;
    const int cb0 = (lg ^ sw) * 16;
    const int cb1 = ((4 + lg) ^ sw) * 16;

    const float MASKED = -3.0f;
    f32x4 acc[8][4];
    float rmax[8][4];
    #pragma unroll
    for (int m = 0; m < 8; ++m)
        #pragma unroll
        for (int n = 0; n < 4; ++n) {
            acc[m][n] = (f32x4){0.f, 0.f, 0.f, 0.f};
            rmax[m][n] = MASKED;   // [m][reg]
        }

    // prologue: step 0 full into buf0; step 1's B0,A1 into buf1
    STAGE_A(0,0,0); STAGE_A(0,1,0); STAGE_B(0,0,0); STAGE_B(0,1,0);
    STAGE_B(1,0,1); STAGE_A(1,1,1);
    GUARD4;

    for (int bi = 0; bi < nt; ++bi) {
        #pragma unroll 1
        for (int j = 0; j < 6; ++j) {
            const int it = bi * 6 + j;
            const int s1 = 2 * it + 1;
            int sA = 2 * it + 2; if (sA > NS - 1) sA = NS - 1;
            int sB = 2 * it + 3; if (sB > NS - 1) sB = NS - 1;

            PHASE(0,0,0, STAGE_A(1,0,s1); STAGE_B(1,1,s1));
            BAR;
            PHASE(0,1,0, );
            BAR;
            PHASE(0,1,1, STAGE_B(0,0,sA));
            BAR;
            PHASE(0,0,1, STAGE_A(0,1,sA));
            GUARD4;
            PHASE(1,0,0, STAGE_A(0,0,sA); STAGE_B(0,1,sA));
            BAR;
            PHASE(1,1,0, );
            BAR;
            PHASE(1,1,1, STAGE_B(1,0,sB));
            BAR;
            PHASE(1,0,1, STAGE_A(1,1,sB));
            GUARD4;
        }

        // ---- per-bn register epilogue (no barriers; overlaps prefetch) ----
        const int bnv = grp + 8 * bi;
        // rowmax accumulate (mask cols >= Fc)
        #pragma unroll
        for (int m = 0; m < 8; ++m)
            #pragma unroll
            for (int reg = 0; reg < 4; ++reg) {
                float v = rmax[m][reg];
                #pragma unroll
                for (int n = 0; n < 4; ++n) {
                    int gc = bnv * 256 + wn * 64 + n * 16 + li;
                    v = fmaxf(v, (gc < Fc) ? acc[m][n][reg] : MASKED);
                }
                rmax[m][reg] = v;
            }
        // colmax flush (mask rows >= R)
        #pragma unroll
        for (int n = 0; n < 4; ++n) {
            float v = MASKED;
            #pragma unroll
            for (int m = 0; m < 8; ++m)
                #pragma unroll
                for (int reg = 0; reg < 4; ++reg) {
                    int gr = bm * 256 + wm * 128 + m * 16 + lg * 4 + reg;
                    v = fmaxf(v, (gr < R) ? acc[m][n][reg] : MASKED);
                }
            v = fmaxf(v, __shfl_xor(v, 16));
            v = fmaxf(v, __shfl_xor(v, 32));
            int gc = bnv * 256 + wn * 64 + n * 16 + li;
            if (lg == 0 && gc < Fc) atomicMax(&colmax[gc], f2u(v));
        }
        // reset acc
        #pragma unroll
        for (int m = 0; m < 8; ++m)
            #pragma unroll
            for (int n = 0; n < 4; ++n)
                acc[m][n] = (f32x4){0.f, 0.f, 0.f, 0.f};
    }

    // ---- final rowmax flush ----
    #pragma unroll
    for (int m = 0; m < 8; ++m)
        #pragma unroll
        for (int reg = 0; reg < 4; ++reg) {
            float v = rmax[m][reg];
            v = fmaxf(v, __shfl_xor(v, 1));
            v = fmaxf(v, __shfl_xor(v, 2));
            v = fmaxf(v, __shfl_xor(v, 4));
            v = fmaxf(v, __shfl_xor(v, 8));
            int gr = bm * 256 + wm * 128 + m * 16 + lg * 4 + reg;
            if (li == 0 && gr < R) atomicMax(&rowmax[gr], f2u(v));
        }
}

// ============================================================================
// K4: maxes -> loss, masked means, scalar out.
// ============================================================================
__global__ void k_final(const u32* __restrict__ rowmax, const u32* __restrict__ colmax,
                        const int* __restrict__ meta, float* __restrict__ out)
{
    const int R = meta[0], Fc = meta[1];
    const int t = threadIdx.x;
    float sr = 0.f, sf = 0.f;
    for (int i = t; i < R; i += 256) {
        u32 u = rowmax[i];
        float m = (u == 0u) ? -1e9f : u2f(u) * INV_TEMP;
        float sg = 1.0f / (1.0f + expf(-m));
        sr += -logf(1.0f - sg + 1e-6f);
    }
    for (int i = t; i < Fc; i += 256) {
        u32 u = colmax[i];
        float m = (u == 0u) ? -1e9f : u2f(u) * INV_TEMP;
        float sg = 1.0f / (1.0f + expf(-m));
        sf += -logf(1.0f - sg + 1e-6f);
    }
    #pragma unroll
    for (int msk = 32; msk >= 1; msk >>= 1) {
        sr += __shfl_xor(sr, msk);
        sf += __shfl_xor(sf, msk);
    }
    __shared__ float r4[4], f4[4];
    if ((t & 63) == 0) { r4[t >> 6] = sr; f4[t >> 6] = sf; }
    __syncthreads();
    if (t == 0) {
        float a = (r4[0] + r4[1] + r4[2] + r4[3]) / (float)((R > 0) ? R : 1);
        float b = (f4[0] + f4[1] + f4[2] + f4[3]) / (float)((Fc > 0) ? Fc : 1);
        out[0] = 0.5f * (a + b);
    }
}

// ============================================================================
extern "C" void kernel_launch(void* const* d_in, const int* in_sizes, int n_in,
                              void* d_out, int out_size, void* d_ws, size_t ws_size,
                              hipStream_t stream)
{
    (void)in_sizes; (void)n_in; (void)out_size; (void)ws_size;
    const float* x    = (const float*)d_in[0];
    const int* labels = (const int*)d_in[1];
    float* out        = (float*)d_out;

    char* ws = (char*)d_ws;
    int* meta = (int*)ws;
    int* pos  = (int*)(ws + 256);
    __hip_bfloat16* Xall = (__hip_bfloat16*)(ws + 131072);
    u32* rowmax = (u32*)(ws + 131072 + XALL_BYTES);
    u32* colmax = rowmax + 16384;

    k_scan<<<1, 256, 0, stream>>>(labels, pos, meta);
    k_norm<<<T_TOK, 256, 0, stream>>>(x, labels, pos, meta, Xall);
    hipMemsetAsync(rowmax, 0, 2 * 16384 * sizeof(u32), stream);
    k_gemm<<<512, 512, 0, stream>>>(Xall, meta, rowmax, colmax);
    k_final<<<1, 256, 0, stream>>>(rowmax, colmax, meta, out);
}